// Round 13
// baseline (329.140 us; speedup 1.0000x reference)
//
#include <hip/hip_runtime.h>
#include <hip/hip_bf16.h>

#define DIM 1024
#define NHEAD 16
#define HD 64
#define SEQ 4096

typedef unsigned short u16;
typedef unsigned int u32;
typedef __attribute__((ext_vector_type(8))) short bf16x8;   // 8 bf16 in 4 VGPRs
typedef __attribute__((ext_vector_type(4))) float f32x4;
typedef __attribute__((ext_vector_type(16))) float f32x16;

__device__ __forceinline__ u16 f2bf(float x) {
  __hip_bfloat16 h = __float2bfloat16(x);
  return *reinterpret_cast<u16*>(&h);
}

__device__ __forceinline__ float bf2f(u16 u) {
  union { u32 u; float f; } c;
  c.u = ((u32)u) << 16;
  return c.f;
}

__device__ __forceinline__ float fexp2(float x) {
#if __has_builtin(__builtin_amdgcn_exp2f)
  return __builtin_amdgcn_exp2f(x);
#else
  return __expf(x * 0.69314718056f);
#endif
}

__device__ __forceinline__ u32 cvtpk(float a, float b) {
  u32 r;
  asm("v_cvt_pk_bf16_f32 %0, %1, %2" : "=v"(r) : "v"(a), "v"(b));
  return r;
}

__device__ __forceinline__ void pswap(u32& a, u32& b) {
  // a' = [a_lo, b_lo], b' = [a_hi, b_hi]  (validated via W-pack;
  // ONLY safe with distinct-value operands — same-value operands may get the
  // same physical register => self-swap. Never build reductions on this.)
  asm("v_permlane32_swap_b32 %0, %1" : "+v"(a), "+v"(b));
}

__device__ __forceinline__ void gload16(const u16* g, const u16* l) {
  __builtin_amdgcn_global_load_lds(
      (const __attribute__((address_space(1))) void*)g,
      (__attribute__((address_space(3))) void*)l, 16, 0, 0);
}

__device__ __forceinline__ float vsum16(const f32x16& v) {
  float a[8];
#pragma unroll
  for (int j = 0; j < 8; ++j) a[j] = v[j] + v[j + 8];
#pragma unroll
  for (int j = 0; j < 4; ++j) a[j] = a[j] + a[j + 4];
  return (a[0] + a[2]) + (a[1] + a[3]);
}

// ---------------- fp32 -> bf16 convert, all 7 tensors in one launch ----------------
__global__ __launch_bounds__(256) void cvt_all(
    const float* __restrict__ q, const float* __restrict__ k, const float* __restrict__ v,
    const float* __restrict__ wq, const float* __restrict__ wk, const float* __restrict__ wv,
    const float* __restrict__ wo,
    u16* __restrict__ oq, u16* __restrict__ ok, u16* __restrict__ ov,
    u16* __restrict__ owq, u16* __restrict__ owk, u16* __restrict__ owv, u16* __restrict__ owo) {
  int b = blockIdx.x;
  const float* in;
  u16* out;
  int i;
  if (b < 12288) {
    int s = b >> 12;
    in = (s == 0) ? q : (s == 1) ? k : v;
    out = (s == 0) ? oq : (s == 1) ? ok : ov;
    i = (b & 4095) * 256 + threadIdx.x;
  } else {
    int bb = b - 12288;
    int s = bb >> 10;
    in = (s == 0) ? wq : (s == 1) ? wk : (s == 2) ? wv : wo;
    out = (s == 0) ? owq : (s == 1) ? owk : (s == 2) ? owv : owo;
    i = (bb & 1023) * 256 + threadIdx.x;
  }
  float4 val = ((const float4*)in)[i];
  ushort4 o;
  o.x = f2bf(val.x); o.y = f2bf(val.y); o.z = f2bf(val.z); o.w = f2bf(val.w);
  ((ushort4*)out)[i] = o;
}

// ---------------- batched projection GEMM (Q, K, Vt) — m97 structure, 128x128 ----------------
// (measured best: 128^2 proj beats 64x128 by ~6us — R12 post-mortem)
__global__ __launch_bounds__(256, 3) void gemm_proj(
    const u16* __restrict__ qx, const u16* __restrict__ kx, const u16* __restrict__ vx,
    const u16* __restrict__ wqp, const u16* __restrict__ wkp, const u16* __restrict__ wvp,
    const float* __restrict__ bq, const float* __restrict__ bk, const float* __restrict__ bv,
    u16* __restrict__ Qb, u16* __restrict__ Kb, u16* __restrict__ Vt) {
  __shared__ u16 As[128][64];
  __shared__ u16 Bs[128][64];
  const int z = blockIdx.y;
  const u16 *Ag, *Bg;
  const float* bias;
  u16* outp;
  int mb, nb;
  float scale = 1.f;
  if (z == 0) {
    Ag = qx; Bg = wqp; bias = bq; outp = Qb;
    mb = blockIdx.x >> 3; nb = blockIdx.x & 7; scale = 0.18033688f;  // 0.125 * log2(e)
  } else if (z == 1) {
    Ag = kx; Bg = wkp; bias = bk; outp = Kb;
    mb = blockIdx.x >> 3; nb = blockIdx.x & 7;
  } else {
    Ag = wvp; Bg = vx; bias = bv; outp = Vt;
    mb = blockIdx.x >> 5; nb = blockIdx.x & 31;
  }

  const int tid = threadIdx.x, lane = tid & 63, wid = tid >> 6;
  const int lq = lane & 15, g = lane >> 4;
  const int wr = wid >> 1, wc = wid & 1;
  const int m0 = mb * 128, n0 = nb * 128;
  const int sr = lane >> 3, ss = lane & 7;

  const u16* pA = Ag + (size_t)(m0 + wid * 32 + sr) * DIM + ((ss ^ sr) * 8);
  const u16* pB = Bg + (size_t)(n0 + wid * 32 + sr) * DIM + ((ss ^ sr) * 8);

  const f32x4 zero4 = {0.f, 0.f, 0.f, 0.f};
  f32x4 acc[4][4];
#pragma unroll
  for (int mi = 0; mi < 4; ++mi)
#pragma unroll
    for (int ni = 0; ni < 4; ++ni) acc[mi][ni] = zero4;

  for (int k0 = 0; k0 < DIM; k0 += 64) {
    __syncthreads();
#pragma unroll
    for (int i = 0; i < 4; ++i) {
      gload16(pA + i * 8 * DIM + k0, &As[wid * 32 + i * 8][0]);
      gload16(pB + i * 8 * DIM + k0, &Bs[wid * 32 + i * 8][0]);
    }
    __syncthreads();
#pragma unroll
    for (int kk = 0; kk < 2; ++kk) {
      bf16x8 a[4], b[4];
#pragma unroll
      for (int t4 = 0; t4 < 4; ++t4) {
        u32 offA = (u32)(wr * 64 + t4 * 16 + lq) * 128 + (u32)(((kk * 4 + g) ^ (lq & 7)) * 16);
        u32 offB = (u32)(wc * 64 + t4 * 16 + lq) * 128 + (u32)(((kk * 4 + g) ^ (lq & 7)) * 16);
        a[t4] = *(const bf16x8*)((const char*)As + offA);
        b[t4] = *(const bf16x8*)((const char*)Bs + offB);
      }
#pragma unroll
      for (int mi = 0; mi < 4; ++mi)
#pragma unroll
        for (int ni = 0; ni < 4; ++ni)
          acc[mi][ni] = __builtin_amdgcn_mfma_f32_16x16x32_bf16(a[mi], b[ni], acc[mi][ni], 0, 0, 0);
    }
  }

  if (z < 2) {
    float bn[4];
#pragma unroll
    for (int ni = 0; ni < 4; ++ni) bn[ni] = bias[n0 + wc * 64 + ni * 16 + lq];
#pragma unroll
    for (int mi = 0; mi < 4; ++mi)
#pragma unroll
      for (int r = 0; r < 4; ++r) {
        int mm = m0 + wr * 64 + mi * 16 + g * 4 + r;
#pragma unroll
        for (int ni = 0; ni < 4; ++ni) {
          int nn = n0 + wc * 64 + ni * 16 + lq;
          float v = (acc[mi][ni][r] + bn[ni]) * scale;
          outp[((size_t)(nn >> 6) * SEQ + mm) * 64 + (nn & 63)] = f2bf(v);
        }
      }
  } else {
#pragma unroll
    for (int mi = 0; mi < 4; ++mi)
#pragma unroll
      for (int r = 0; r < 4; ++r) {
        int mm = m0 + wr * 64 + mi * 16 + g * 4 + r;
        float bm = bias[mm];
#pragma unroll
        for (int ni = 0; ni < 4; ++ni) {
          int nn = n0 + wc * 64 + ni * 16 + lq;
          outp[(size_t)mm * SEQ + nn] = f2bf(acc[mi][ni][r] + bm);
        }
      }
  }
}

// ---------------- output projection GEMM (f32 out) — 64x128 tile, 512 blocks ----------------
__global__ __launch_bounds__(256, 2) void gemm_out(
    const u16* __restrict__ Ag, const u16* __restrict__ Bg,
    const float* __restrict__ bias, float* __restrict__ outp) {
  __shared__ u16 As[64][64];
  __shared__ u16 Bs[128][64];
  const int tid = threadIdx.x, lane = tid & 63, wid = tid >> 6;
  const int lq = lane & 15, g = lane >> 4;
  const int wr = wid >> 1, wc = wid & 1;
  const int m0 = blockIdx.x * 64, n0 = blockIdx.y * 128;
  const int sr = lane >> 3, ss = lane & 7;

  const u16* pA = Ag + (size_t)(m0 + wid * 16 + sr) * DIM + ((ss ^ sr) * 8);
  const u16* pB = Bg + (size_t)(n0 + wid * 32 + sr) * DIM + ((ss ^ sr) * 8);

  const f32x4 zero4 = {0.f, 0.f, 0.f, 0.f};
  f32x4 acc[2][4];
#pragma unroll
  for (int mi = 0; mi < 2; ++mi)
#pragma unroll
    for (int ni = 0; ni < 4; ++ni) acc[mi][ni] = zero4;

  for (int k0 = 0; k0 < DIM; k0 += 64) {
    __syncthreads();
#pragma unroll
    for (int i = 0; i < 2; ++i)
      gload16(pA + i * 8 * DIM + k0, &As[wid * 16 + i * 8][0]);
#pragma unroll
    for (int i = 0; i < 4; ++i)
      gload16(pB + i * 8 * DIM + k0, &Bs[wid * 32 + i * 8][0]);
    __syncthreads();
#pragma unroll
    for (int kk = 0; kk < 2; ++kk) {
      bf16x8 a[2], b[4];
#pragma unroll
      for (int t4 = 0; t4 < 2; ++t4) {
        u32 offA = (u32)(wr * 32 + t4 * 16 + lq) * 128 + (u32)(((kk * 4 + g) ^ (lq & 7)) * 16);
        a[t4] = *(const bf16x8*)((const char*)As + offA);
      }
#pragma unroll
      for (int t4 = 0; t4 < 4; ++t4) {
        u32 offB = (u32)(wc * 64 + t4 * 16 + lq) * 128 + (u32)(((kk * 4 + g) ^ (lq & 7)) * 16);
        b[t4] = *(const bf16x8*)((const char*)Bs + offB);
      }
#pragma unroll
      for (int mi = 0; mi < 2; ++mi)
#pragma unroll
        for (int ni = 0; ni < 4; ++ni)
          acc[mi][ni] = __builtin_amdgcn_mfma_f32_16x16x32_bf16(a[mi], b[ni], acc[mi][ni], 0, 0, 0);
    }
  }

  float bn[4];
#pragma unroll
  for (int ni = 0; ni < 4; ++ni) bn[ni] = bias[n0 + wc * 64 + ni * 16 + lq];
#pragma unroll
  for (int mi = 0; mi < 2; ++mi)
#pragma unroll
    for (int r = 0; r < 4; ++r) {
      int mm = m0 + wr * 32 + mi * 16 + g * 4 + r;
#pragma unroll
      for (int ni = 0; ni < 4; ++ni) {
        int nn = n0 + wc * 64 + ni * 16 + lq;
        outp[(size_t)mm * DIM + nn] = acc[mi][ni][r] + bn[ni];
      }
    }
}

// ---------------- flash attention, 64 q/wave, KV-split x2, software-pipelined ----------------
// 4 LDS buffers; per iteration t: {prefetch(t+1); QK(t) [MFMA]; PV(t-1) [MFMA,
// independent of QK(t)]; exp/pack(t) [VALU — executes while PV MFMAs run]}.
// W double-buffered (We/Wo). Math identical to R12 (static-max exp2 softmax).
__global__ __launch_bounds__(256, 2) void attn32(
    const u16* __restrict__ Qb, const u16* __restrict__ Kb,
    const u16* __restrict__ Vtb, u16* __restrict__ po,
    float* __restrict__ pl) {
  __shared__ u16 Ks[4][64][64];
  __shared__ u16 Vs[4][64][64];
  const int tid = threadIdx.x, lane = tid & 63, wid = tid >> 6;
  const int q5 = lane & 31, hi = lane >> 5;
  const int bid = blockIdx.x;                     // 512 blocks
  const int rest = bid >> 3;                      // 0..63
  const int h = (bid & 7) * 2 + (rest >> 5);      // XCD-aware: 2 heads per XCD
  const int kv = (rest >> 4) & 1;                 // KV half
  const int qbase = (rest & 15) * 256 + wid * 64;

  const u16* Qg = Qb + (size_t)h * SEQ * HD;
  const u16* Kg = Kb + (size_t)h * SEQ * HD;
  const u16* Vg = Vtb + (size_t)h * HD * SEQ;

  const int sr = lane >> 3, ss = lane & 7;
  const u16* pK = Kg + (size_t)(kv * 2048 + wid * 16 + sr) * HD + ((ss ^ sr) * 8);
  const u16* pV = Vg + (size_t)(wid * 16 + sr) * SEQ + kv * 2048 + ((ss ^ sr) * 8);

  u32 roff[8];
#pragma unroll
  for (int ks = 0; ks < 4; ++ks) {
    u32 slot = (u32)((ks * 2 + hi) ^ (q5 & 7));
    roff[ks * 2] = (u32)q5 * 128 + slot * 16;
    roff[ks * 2 + 1] = (u32)(32 + q5) * 128 + slot * 16;
  }
  const char* KsB = (const char*)Ks;
  const char* VsB = (const char*)Vs;

  bf16x8 qfA[4], qfB[4];
#pragma unroll
  for (int ks = 0; ks < 4; ++ks) {
    qfA[ks] = *(const bf16x8*)(Qg + (size_t)(qbase + q5) * HD + ks * 16 + hi * 8);
    qfB[ks] = *(const bf16x8*)(Qg + (size_t)(qbase + 32 + q5) * HD + ks * 16 + hi * 8);
  }

  f32x16 oA0, oA1, oB0, oB1, zv;
#pragma unroll
  for (int j = 0; j < 16; ++j) {
    oA0[j] = 0.f; oA1[j] = 0.f; oB0[j] = 0.f; oB1[j] = 0.f; zv[j] = 0.f;
  }
  float lsumA = 0.f, lsumB = 0.f;
  f32x16 sA0, sA1, sB0, sB1;
  bf16x8 WeA[4], WeB[4], WoA[4], WoB[4];

  const int NT = 2048 / 64;  // 32 tiles per KV half

#define PF(tt, cb)                                                            \
  {                                                                           \
    const u16* gk = pK + (size_t)(tt) * (64 * HD);                            \
    const u16* gv = pV + (tt) * 64;                                           \
    gload16(gk, &Ks[cb][wid * 16][0]);                                        \
    gload16(gk + 8 * HD, &Ks[cb][wid * 16 + 8][0]);                           \
    gload16(gv, &Vs[cb][wid * 16][0]);                                        \
    gload16(gv + 8 * SEQ, &Vs[cb][wid * 16 + 8][0]);                          \
  }

#define QKSTEP(cb)                                                            \
  {                                                                           \
    __builtin_amdgcn_s_setprio(1);                                            \
    {                                                                         \
      bf16x8 ka0 = *(const bf16x8*)(KsB + (cb) * 8192 + roff[0]);             \
      bf16x8 ka1 = *(const bf16x8*)(KsB + (cb) * 8192 + roff[1]);             \
      sA0 = __builtin_amdgcn_mfma_f32_32x32x16_bf16(ka0, qfA[0], zv, 0, 0, 0);\
      sA1 = __builtin_amdgcn_mfma_f32_32x32x16_bf16(ka1, qfA[0], zv, 0, 0, 0);\
      sB0 = __builtin_amdgcn_mfma_f32_32x32x16_bf16(ka0, qfB[0], zv, 0, 0, 0);\
      sB1 = __builtin_amdgcn_mfma_f32_32x32x16_bf16(ka1, qfB[0], zv, 0, 0, 0);\
    }                                                                         \
    _Pragma("unroll")                                                         \
    for (int ks = 1; ks < 4; ++ks) {                                          \
      bf16x8 ka0 = *(const bf16x8*)(KsB + (cb) * 8192 + roff[ks * 2]);        \
      bf16x8 ka1 = *(const bf16x8*)(KsB + (cb) * 8192 + roff[ks * 2 + 1]);    \
      sA0 = __builtin_amdgcn_mfma_f32_32x32x16_bf16(ka0, qfA[ks], sA0, 0, 0, 0);\
      sA1 = __builtin_amdgcn_mfma_f32_32x32x16_bf16(ka1, qfA[ks], sA1, 0, 0, 0);\
      sB0 = __builtin_amdgcn_mfma_f32_32x32x16_bf16(ka0, qfB[ks], sB0, 0, 0, 0);\
      sB1 = __builtin_amdgcn_mfma_f32_32x32x16_bf16(ka1, qfB[ks], sB1, 0, 0, 0);\
    }                                                                         \
    __builtin_amdgcn_s_setprio(0);                                            \
  }

#define PVSTEP(cb, WA, WB)                                                    \
  {                                                                           \
    __builtin_amdgcn_s_setprio(1);                                            \
    _Pragma("unroll")                                                         \
    for (int ks = 0; ks < 4; ++ks) {                                          \
      bf16x8 va0 = *(const bf16x8*)(VsB + (cb) * 8192 + roff[ks * 2]);        \
      bf16x8 va1 = *(const bf16x8*)(VsB + (cb) * 8192 + roff[ks * 2 + 1]);    \
      oA0 = __builtin_amdgcn_mfma_f32_32x32x16_bf16(va0, WA[ks], oA0, 0, 0, 0);\
      oA1 = __builtin_amdgcn_mfma_f32_32x32x16_bf16(va1, WA[ks], oA1, 0, 0, 0);\
      oB0 = __builtin_amdgcn_mfma_f32_32x32x16_bf16(va0, WB[ks], oB0, 0, 0, 0);\
      oB1 = __builtin_amdgcn_mfma_f32_32x32x16_bf16(va1, WB[ks], oB1, 0, 0, 0);\
    }                                                                         \
    __builtin_amdgcn_s_setprio(0);                                            \
  }

#define PACK1(W, pk0, pk1)                                                    \
  _Pragma("unroll")                                                           \
  for (int kss = 0; kss < 2; ++kss) {                                         \
    {                                                                         \
      u32 a = pk0[4 * kss], b = pk0[4 * kss + 2];                             \
      u32 c = pk0[4 * kss + 1], d = pk0[4 * kss + 3];                         \
      pswap(a, b);                                                            \
      pswap(c, d);                                                            \
      union { u32 u[4]; bf16x8 v; } tt;                                       \
      tt.u[0] = a; tt.u[1] = c; tt.u[2] = b; tt.u[3] = d;                     \
      W[kss] = tt.v;                                                          \
    }                                                                         \
    {                                                                         \
      u32 a = pk1[4 * kss], b = pk1[4 * kss + 2];                             \
      u32 c = pk1[4 * kss + 1], d = pk1[4 * kss + 3];                         \
      pswap(a, b);                                                            \
      pswap(c, d);                                                            \
      union { u32 u[4]; bf16x8 v; } tt;                                       \
      tt.u[0] = a; tt.u[1] = c; tt.u[2] = b; tt.u[3] = d;                     \
      W[2 + kss] = tt.v;                                                      \
    }                                                                         \
  }

#define EXPPACK(WA, WB)                                                       \
  {                                                                           \
    _Pragma("unroll")                                                         \
    for (int j = 0; j < 16; ++j) sA0[j] = fexp2(sA0[j]);                      \
    _Pragma("unroll")                                                         \
    for (int j = 0; j < 16; ++j) sA1[j] = fexp2(sA1[j]);                      \
    _Pragma("unroll")                                                         \
    for (int j = 0; j < 16; ++j) sB0[j] = fexp2(sB0[j]);                      \
    _Pragma("unroll")                                                         \
    for (int j = 0; j < 16; ++j) sB1[j] = fexp2(sB1[j]);                      \
    lsumA += vsum16(sA0) + vsum16(sA1);                                       \
    lsumB += vsum16(sB0) + vsum16(sB1);                                       \
    u32 pkA0[8], pkA1[8], pkB0[8], pkB1[8];                                   \
    _Pragma("unroll")                                                         \
    for (int i2 = 0; i2 < 8; ++i2) {                                          \
      pkA0[i2] = cvtpk(sA0[2 * i2], sA0[2 * i2 + 1]);                         \
      pkA1[i2] = cvtpk(sA1[2 * i2], sA1[2 * i2 + 1]);                         \
      pkB0[i2] = cvtpk(sB0[2 * i2], sB0[2 * i2 + 1]);                         \
      pkB1[i2] = cvtpk(sB1[2 * i2], sB1[2 * i2 + 1]);                         \
    }                                                                         \
    PACK1(WA, pkA0, pkA1)                                                     \
    PACK1(WB, pkB0, pkB1)                                                     \
  }

// r: compile-time phase 0..3 (buffers: QK=r, PV=(r+3)&3, PF=(r+1)&3)
#define BODY(r, DO_PF, DO_PV, WCA, WCB, WPA, WPB)                             \
  {                                                                           \
    if (DO_PF) PF(tbase + (r) + 1, ((r) + 1) & 3);                            \
    QKSTEP((r) & 3);                                                          \
    if (DO_PV) PVSTEP(((r) + 3) & 3, WPA, WPB);                               \
    EXPPACK(WCA, WCB);                                                        \
    __syncthreads();                                                          \
  }

  PF(0, 0);
  __syncthreads();

  for (int tbase = 0; tbase < NT; tbase += 4) {
    BODY(0, true, tbase > 0, WeA, WeB, WoA, WoB);
    BODY(1, true, true, WoA, WoB, WeA, WeB);
    BODY(2, true, true, WeA, WeB, WoA, WoB);
    BODY(3, tbase + 4 < NT, true, WoA, WoB, WeA, WeB);
  }
  // epilogue: PV for the final tile (buf (NT-1)&3 = 3, W = last cur = Wo)
  PVSTEP(3, WoA, WoB);

#undef BODY
#undef EXPPACK
#undef PACK1
#undef PVSTEP
#undef QKSTEP
#undef PF

  // epilogue: one cross-half reduce per q-block, then normalized partial o
  lsumA += __shfl_xor(lsumA, 32);
  lsumB += __shfl_xor(lsumB, 32);
  float invA = 1.f / lsumA;
  float invB = 1.f / lsumB;
  size_t ridxA = (size_t)(kv * 16 + h) * 4096 + qbase + q5;
  size_t ridxB = ridxA + 32;
  u16* cpA = po + ridxA * 64;
  u16* cpB = po + ridxB * 64;
#pragma unroll
  for (int rg = 0; rg < 4; ++rg) {
    ushort4 pa, pb;
    pa.x = f2bf(oA0[rg * 4 + 0] * invA); pa.y = f2bf(oA0[rg * 4 + 1] * invA);
    pa.z = f2bf(oA0[rg * 4 + 2] * invA); pa.w = f2bf(oA0[rg * 4 + 3] * invA);
    pb.x = f2bf(oA1[rg * 4 + 0] * invA); pb.y = f2bf(oA1[rg * 4 + 1] * invA);
    pb.z = f2bf(oA1[rg * 4 + 2] * invA); pb.w = f2bf(oA1[rg * 4 + 3] * invA);
    *(ushort4*)(cpA + rg * 8 + 4 * hi) = pa;
    *(ushort4*)(cpA + 32 + rg * 8 + 4 * hi) = pb;
    pa.x = f2bf(oB0[rg * 4 + 0] * invB); pa.y = f2bf(oB0[rg * 4 + 1] * invB);
    pa.z = f2bf(oB0[rg * 4 + 2] * invB); pa.w = f2bf(oB0[rg * 4 + 3] * invB);
    pb.x = f2bf(oB1[rg * 4 + 0] * invB); pb.y = f2bf(oB1[rg * 4 + 1] * invB);
    pb.z = f2bf(oB1[rg * 4 + 2] * invB); pb.w = f2bf(oB1[rg * 4 + 3] * invB);
    *(ushort4*)(cpB + rg * 8 + 4 * hi) = pa;
    *(ushort4*)(cpB + 32 + rg * 8 + 4 * hi) = pb;
  }
  if (hi == 0) {
    pl[ridxA] = lsumA;
    pl[ridxB] = lsumB;
  }
}

// ---------------- combine two KV-half partials -> ctx ----------------
__global__ __launch_bounds__(256) void combine(
    const u16* __restrict__ po, const float* __restrict__ pl,
    u16* __restrict__ cx) {
  const int tid = threadIdx.x;
  const int R = blockIdx.x * 64 + (tid >> 2);   // row = h*4096 + q
  const int h = R >> 12, q = R & 4095;
  const int dbase = (tid & 3) * 16;
  const int idx0 = R;
  const int idx1 = R + 16 * 4096;
  float l0 = pl[idx0], l1 = pl[idx1];
  float inv = 1.f / (l0 + l1);
  float a0 = l0 * inv, a1 = l1 * inv;
  const u16* p0 = po + (size_t)idx0 * 64 + dbase;
  const u16* p1 = po + (size_t)idx1 * 64 + dbase;
  u16* cp = cx + (size_t)q * DIM + h * 64 + dbase;
#pragma unroll
  for (int v = 0; v < 2; ++v) {
    bf16x8 x0 = *(const bf16x8*)(p0 + v * 8);
    bf16x8 x1 = *(const bf16x8*)(p1 + v * 8);
    union { u16 u[8]; bf16x8 v8; } r;
#pragma unroll
    for (int j = 0; j < 8; ++j)
      r.u[j] = f2bf(a0 * bf2f((u16)x0[j]) + a1 * bf2f((u16)x1[j]));
    *(bf16x8*)(cp + v * 8) = r.v8;
  }
}

extern "C" void kernel_launch(void* const* d_in, const int* in_sizes, int n_in,
                              void* d_out, int out_size, void* d_ws, size_t ws_size,
                              hipStream_t stream) {
  const float* query = (const float*)d_in[0];
  const float* key_  = (const float*)d_in[1];
  const float* value = (const float*)d_in[2];
  const float* Wq = (const float*)d_in[3]; const float* bq = (const float*)d_in[4];
  const float* Wk = (const float*)d_in[5]; const float* bk = (const float*)d_in[6];
  const float* Wv = (const float*)d_in[7]; const float* bv = (const float*)d_in[8];
  const float* Wo = (const float*)d_in[9]; const float* bo = (const float*)d_in[10];

  char* ws = (char*)d_ws;
  const size_t MB = 1024 * 1024;
  u16* qx = (u16*)(ws);            // 8MB  (dead after gemm_proj)
  u16* kx = (u16*)(ws + 8 * MB);   // 8MB  (dead after gemm_proj)
  u16* vx = (u16*)(ws + 16 * MB);  // 8MB  (dead after gemm_proj)
  u16* wq = (u16*)(ws + 24 * MB);  // 2MB
  u16* wk = (u16*)(ws + 26 * MB);
  u16* wv = (u16*)(ws + 28 * MB);
  u16* wo = (u16*)(ws + 30 * MB);  // live until gemm_out
  u16* Qb = (u16*)(ws + 32 * MB);  // 8MB  (h, s, d)  pre-scaled by 0.125*log2(e)
  u16* Kb = (u16*)(ws + 40 * MB);  // 8MB  (h, l, d)
  u16* Vt = (u16*)(ws + 48 * MB);  // 8MB  (h, d, l)
  u16* cx = (u16*)(ws + 56 * MB);  // 8MB  ctx bf16 (s, DIM)
  u16* po = (u16*)(ws);            // 16MB partial o [kv][h][q][64] (overlaps qx/kx)
  float* pl = (float*)(ws + 16 * MB);  // 512KB [kv][h][q]

  cvt_all<<<dim3(16384), 256, 0, stream>>>(query, key_, value, Wq, Wk, Wv, Wo,
                                           qx, kx, vx, wq, wk, wv, wo);

  gemm_proj<<<dim3(256, 3), 256, 0, stream>>>(qx, kx, vx, wq, wk, wv,
                                              bq, bk, bv, Qb, Kb, Vt);

  attn32<<<dim3(512), 256, 0, stream>>>(Qb, Kb, Vt, po, pl);

  combine<<<dim3(1024), 256, 0, stream>>>(po, pl, cx);

  gemm_out<<<dim3(64, 8), 256, 0, stream>>>(cx, wo, bo, (float*)d_out);
}

// Round 14
// 153.358 us; speedup vs baseline: 2.1462x; 2.1462x over previous
//
#include <hip/hip_runtime.h>
#include <hip/hip_bf16.h>

#define DIM 1024
#define NHEAD 16
#define HD 64
#define SEQ 4096

typedef unsigned short u16;
typedef unsigned int u32;
typedef __attribute__((ext_vector_type(8))) short bf16x8;   // 8 bf16 in 4 VGPRs
typedef __attribute__((ext_vector_type(4))) float f32x4;
typedef __attribute__((ext_vector_type(16))) float f32x16;

__device__ __forceinline__ u16 f2bf(float x) {
  __hip_bfloat16 h = __float2bfloat16(x);
  return *reinterpret_cast<u16*>(&h);
}

__device__ __forceinline__ float bf2f(u16 u) {
  union { u32 u; float f; } c;
  c.u = ((u32)u) << 16;
  return c.f;
}

__device__ __forceinline__ float fexp2(float x) {
#if __has_builtin(__builtin_amdgcn_exp2f)
  return __builtin_amdgcn_exp2f(x);
#else
  return __expf(x * 0.69314718056f);
#endif
}

__device__ __forceinline__ u32 cvtpk(float a, float b) {
  u32 r;
  asm("v_cvt_pk_bf16_f32 %0, %1, %2" : "=v"(r) : "v"(a), "v"(b));
  return r;
}

__device__ __forceinline__ void pswap(u32& a, u32& b) {
  // a' = [a_lo, b_lo], b' = [a_hi, b_hi]  (validated via W-pack;
  // ONLY safe with distinct-value operands — same-value operands may get the
  // same physical register => self-swap. Never build reductions on this.)
  asm("v_permlane32_swap_b32 %0, %1" : "+v"(a), "+v"(b));
}

__device__ __forceinline__ void gload16(const u16* g, const u16* l) {
  __builtin_amdgcn_global_load_lds(
      (const __attribute__((address_space(1))) void*)g,
      (__attribute__((address_space(3))) void*)l, 16, 0, 0);
}

__device__ __forceinline__ float vsum16(const f32x16& v) {
  float a[8];
#pragma unroll
  for (int j = 0; j < 8; ++j) a[j] = v[j] + v[j + 8];
#pragma unroll
  for (int j = 0; j < 4; ++j) a[j] = a[j] + a[j + 4];
  return (a[0] + a[2]) + (a[1] + a[3]);
}

// ---------------- fp32 -> bf16 convert, all 7 tensors in one launch ----------------
__global__ __launch_bounds__(256) void cvt_all(
    const float* __restrict__ q, const float* __restrict__ k, const float* __restrict__ v,
    const float* __restrict__ wq, const float* __restrict__ wk, const float* __restrict__ wv,
    const float* __restrict__ wo,
    u16* __restrict__ oq, u16* __restrict__ ok, u16* __restrict__ ov,
    u16* __restrict__ owq, u16* __restrict__ owk, u16* __restrict__ owv, u16* __restrict__ owo) {
  int b = blockIdx.x;
  const float* in;
  u16* out;
  int i;
  if (b < 12288) {
    int s = b >> 12;
    in = (s == 0) ? q : (s == 1) ? k : v;
    out = (s == 0) ? oq : (s == 1) ? ok : ov;
    i = (b & 4095) * 256 + threadIdx.x;
  } else {
    int bb = b - 12288;
    int s = bb >> 10;
    in = (s == 0) ? wq : (s == 1) ? wk : (s == 2) ? wv : wo;
    out = (s == 0) ? owq : (s == 1) ? owk : (s == 2) ? owv : owo;
    i = (bb & 1023) * 256 + threadIdx.x;
  }
  float4 val = ((const float4*)in)[i];
  ushort4 o;
  o.x = f2bf(val.x); o.y = f2bf(val.y); o.z = f2bf(val.z); o.w = f2bf(val.w);
  ((ushort4*)out)[i] = o;
}

// ---------------- batched projection GEMM (Q, K, Vt) — m97 structure, 128x128 ----------------
// (measured best: 128^2 batched proj; 64x128 variant cost +6us — R12 post-mortem)
__global__ __launch_bounds__(256, 3) void gemm_proj(
    const u16* __restrict__ qx, const u16* __restrict__ kx, const u16* __restrict__ vx,
    const u16* __restrict__ wqp, const u16* __restrict__ wkp, const u16* __restrict__ wvp,
    const float* __restrict__ bq, const float* __restrict__ bk, const float* __restrict__ bv,
    u16* __restrict__ Qb, u16* __restrict__ Kb, u16* __restrict__ Vt) {
  __shared__ u16 As[128][64];
  __shared__ u16 Bs[128][64];
  const int z = blockIdx.y;
  const u16 *Ag, *Bg;
  const float* bias;
  u16* outp;
  int mb, nb;
  float scale = 1.f;
  if (z == 0) {
    Ag = qx; Bg = wqp; bias = bq; outp = Qb;
    mb = blockIdx.x >> 3; nb = blockIdx.x & 7; scale = 0.18033688f;  // 0.125 * log2(e)
  } else if (z == 1) {
    Ag = kx; Bg = wkp; bias = bk; outp = Kb;
    mb = blockIdx.x >> 3; nb = blockIdx.x & 7;
  } else {
    Ag = wvp; Bg = vx; bias = bv; outp = Vt;
    mb = blockIdx.x >> 5; nb = blockIdx.x & 31;
  }

  const int tid = threadIdx.x, lane = tid & 63, wid = tid >> 6;
  const int lq = lane & 15, g = lane >> 4;
  const int wr = wid >> 1, wc = wid & 1;
  const int m0 = mb * 128, n0 = nb * 128;
  const int sr = lane >> 3, ss = lane & 7;

  const u16* pA = Ag + (size_t)(m0 + wid * 32 + sr) * DIM + ((ss ^ sr) * 8);
  const u16* pB = Bg + (size_t)(n0 + wid * 32 + sr) * DIM + ((ss ^ sr) * 8);

  const f32x4 zero4 = {0.f, 0.f, 0.f, 0.f};
  f32x4 acc[4][4];
#pragma unroll
  for (int mi = 0; mi < 4; ++mi)
#pragma unroll
    for (int ni = 0; ni < 4; ++ni) acc[mi][ni] = zero4;

  for (int k0 = 0; k0 < DIM; k0 += 64) {
    __syncthreads();
#pragma unroll
    for (int i = 0; i < 4; ++i) {
      gload16(pA + i * 8 * DIM + k0, &As[wid * 32 + i * 8][0]);
      gload16(pB + i * 8 * DIM + k0, &Bs[wid * 32 + i * 8][0]);
    }
    __syncthreads();
#pragma unroll
    for (int kk = 0; kk < 2; ++kk) {
      bf16x8 a[4], b[4];
#pragma unroll
      for (int t4 = 0; t4 < 4; ++t4) {
        u32 offA = (u32)(wr * 64 + t4 * 16 + lq) * 128 + (u32)(((kk * 4 + g) ^ (lq & 7)) * 16);
        u32 offB = (u32)(wc * 64 + t4 * 16 + lq) * 128 + (u32)(((kk * 4 + g) ^ (lq & 7)) * 16);
        a[t4] = *(const bf16x8*)((const char*)As + offA);
        b[t4] = *(const bf16x8*)((const char*)Bs + offB);
      }
#pragma unroll
      for (int mi = 0; mi < 4; ++mi)
#pragma unroll
        for (int ni = 0; ni < 4; ++ni)
          acc[mi][ni] = __builtin_amdgcn_mfma_f32_16x16x32_bf16(a[mi], b[ni], acc[mi][ni], 0, 0, 0);
    }
  }

  if (z < 2) {
    float bn[4];
#pragma unroll
    for (int ni = 0; ni < 4; ++ni) bn[ni] = bias[n0 + wc * 64 + ni * 16 + lq];
#pragma unroll
    for (int mi = 0; mi < 4; ++mi)
#pragma unroll
      for (int r = 0; r < 4; ++r) {
        int mm = m0 + wr * 64 + mi * 16 + g * 4 + r;
#pragma unroll
        for (int ni = 0; ni < 4; ++ni) {
          int nn = n0 + wc * 64 + ni * 16 + lq;
          float v = (acc[mi][ni][r] + bn[ni]) * scale;
          outp[((size_t)(nn >> 6) * SEQ + mm) * 64 + (nn & 63)] = f2bf(v);
        }
      }
  } else {
#pragma unroll
    for (int mi = 0; mi < 4; ++mi)
#pragma unroll
      for (int r = 0; r < 4; ++r) {
        int mm = m0 + wr * 64 + mi * 16 + g * 4 + r;
        float bm = bias[mm];
#pragma unroll
        for (int ni = 0; ni < 4; ++ni) {
          int nn = n0 + wc * 64 + ni * 16 + lq;
          outp[(size_t)mm * SEQ + nn] = f2bf(acc[mi][ni][r] + bm);
        }
      }
  }
}

// ---------------- output projection GEMM (f32 out) — 64x128 tile, 512 blocks ----------------
__global__ __launch_bounds__(256, 2) void gemm_out(
    const u16* __restrict__ Ag, const u16* __restrict__ Bg,
    const float* __restrict__ bias, float* __restrict__ outp) {
  __shared__ u16 As[64][64];
  __shared__ u16 Bs[128][64];
  const int tid = threadIdx.x, lane = tid & 63, wid = tid >> 6;
  const int lq = lane & 15, g = lane >> 4;
  const int wr = wid >> 1, wc = wid & 1;
  const int m0 = blockIdx.x * 64, n0 = blockIdx.y * 128;
  const int sr = lane >> 3, ss = lane & 7;

  const u16* pA = Ag + (size_t)(m0 + wid * 16 + sr) * DIM + ((ss ^ sr) * 8);
  const u16* pB = Bg + (size_t)(n0 + wid * 32 + sr) * DIM + ((ss ^ sr) * 8);

  const f32x4 zero4 = {0.f, 0.f, 0.f, 0.f};
  f32x4 acc[2][4];
#pragma unroll
  for (int mi = 0; mi < 2; ++mi)
#pragma unroll
    for (int ni = 0; ni < 4; ++ni) acc[mi][ni] = zero4;

  for (int k0 = 0; k0 < DIM; k0 += 64) {
    __syncthreads();
#pragma unroll
    for (int i = 0; i < 2; ++i)
      gload16(pA + i * 8 * DIM + k0, &As[wid * 16 + i * 8][0]);
#pragma unroll
    for (int i = 0; i < 4; ++i)
      gload16(pB + i * 8 * DIM + k0, &Bs[wid * 32 + i * 8][0]);
    __syncthreads();
#pragma unroll
    for (int kk = 0; kk < 2; ++kk) {
      bf16x8 a[2], b[4];
#pragma unroll
      for (int t4 = 0; t4 < 2; ++t4) {
        u32 offA = (u32)(wr * 32 + t4 * 16 + lq) * 128 + (u32)(((kk * 4 + g) ^ (lq & 7)) * 16);
        a[t4] = *(const bf16x8*)((const char*)As + offA);
      }
#pragma unroll
      for (int t4 = 0; t4 < 4; ++t4) {
        u32 offB = (u32)(wc * 64 + t4 * 16 + lq) * 128 + (u32)(((kk * 4 + g) ^ (lq & 7)) * 16);
        b[t4] = *(const bf16x8*)((const char*)Bs + offB);
      }
#pragma unroll
      for (int mi = 0; mi < 2; ++mi)
#pragma unroll
        for (int ni = 0; ni < 4; ++ni)
          acc[mi][ni] = __builtin_amdgcn_mfma_f32_16x16x32_bf16(a[mi], b[ni], acc[mi][ni], 0, 0, 0);
    }
  }

  float bn[4];
#pragma unroll
  for (int ni = 0; ni < 4; ++ni) bn[ni] = bias[n0 + wc * 64 + ni * 16 + lq];
#pragma unroll
  for (int mi = 0; mi < 2; ++mi)
#pragma unroll
    for (int r = 0; r < 4; ++r) {
      int mm = m0 + wr * 32 + mi * 16 + g * 4 + r;
#pragma unroll
      for (int ni = 0; ni < 4; ++ni) {
        int nn = n0 + wc * 64 + ni * 16 + lq;
        outp[(size_t)mm * DIM + nn] = acc[mi][ni][r] + bn[ni];
      }
    }
}

// ---------------- flash attention, 64 q/wave, KV-split x2, static-max ----------------
// R12-exact, measured 79.9us (VGPR 120, no spill). Register budget note (R9+R13
// lessons): this structure sits at ~184 unified regs/wave; ANY cross-tile
// pipelining state (+W dbuf, +live s across PV) exceeds the 2-wave/SIMD 256-reg
// budget and spills catastrophically. Do not add pipeline state at 64q/wave.
__global__ __launch_bounds__(256, 2) void attn32(
    const u16* __restrict__ Qb, const u16* __restrict__ Kb,
    const u16* __restrict__ Vtb, u16* __restrict__ po,
    float* __restrict__ pl) {
  __shared__ u16 Ks[2][64][64];
  __shared__ u16 Vs[2][64][64];
  const int tid = threadIdx.x, lane = tid & 63, wid = tid >> 6;
  const int q5 = lane & 31, hi = lane >> 5;
  const int bid = blockIdx.x;                     // 512 blocks
  const int rest = bid >> 3;                      // 0..63
  const int h = (bid & 7) * 2 + (rest >> 5);      // XCD-aware: 2 heads per XCD
  const int kv = (rest >> 4) & 1;                 // KV half
  const int qbase = (rest & 15) * 256 + wid * 64;

  const u16* Qg = Qb + (size_t)h * SEQ * HD;
  const u16* Kg = Kb + (size_t)h * SEQ * HD;
  const u16* Vg = Vtb + (size_t)h * HD * SEQ;

  const int sr = lane >> 3, ss = lane & 7;
  const u16* pK = Kg + (size_t)(kv * 2048 + wid * 16 + sr) * HD + ((ss ^ sr) * 8);
  const u16* pV = Vg + (size_t)(wid * 16 + sr) * SEQ + kv * 2048 + ((ss ^ sr) * 8);

  u32 roff[8];
#pragma unroll
  for (int ks = 0; ks < 4; ++ks) {
    u32 slot = (u32)((ks * 2 + hi) ^ (q5 & 7));
    roff[ks * 2] = (u32)q5 * 128 + slot * 16;
    roff[ks * 2 + 1] = (u32)(32 + q5) * 128 + slot * 16;
  }
  const char* KsB = (const char*)Ks;
  const char* VsB = (const char*)Vs;

  bf16x8 qfA[4], qfB[4];
#pragma unroll
  for (int ks = 0; ks < 4; ++ks) {
    qfA[ks] = *(const bf16x8*)(Qg + (size_t)(qbase + q5) * HD + ks * 16 + hi * 8);
    qfB[ks] = *(const bf16x8*)(Qg + (size_t)(qbase + 32 + q5) * HD + ks * 16 + hi * 8);
  }

  f32x16 oA0, oA1, oB0, oB1, zv;
#pragma unroll
  for (int j = 0; j < 16; ++j) {
    oA0[j] = 0.f; oA1[j] = 0.f; oB0[j] = 0.f; oB1[j] = 0.f; zv[j] = 0.f;
  }
  float lsumA = 0.f, lsumB = 0.f;

  gload16(pK, &Ks[0][wid * 16][0]);
  gload16(pK + 8 * HD, &Ks[0][wid * 16 + 8][0]);
  gload16(pV, &Vs[0][wid * 16][0]);
  gload16(pV + 8 * SEQ, &Vs[0][wid * 16 + 8][0]);
  const u16* pKn = pK + 64 * HD;
  const u16* pVn = pV + 64;
  __syncthreads();

  const int NT = 2048 / 64;  // 32 tiles per KV half

#define PACK_W(W, pk0, pk1)                                                   \
  _Pragma("unroll")                                                           \
  for (int kss = 0; kss < 2; ++kss) {                                         \
    {                                                                         \
      u32 a = pk0[4 * kss], b = pk0[4 * kss + 2];                             \
      u32 c = pk0[4 * kss + 1], d = pk0[4 * kss + 3];                         \
      pswap(a, b);                                                            \
      pswap(c, d);                                                            \
      union { u32 u[4]; bf16x8 v; } tt;                                       \
      tt.u[0] = a; tt.u[1] = c; tt.u[2] = b; tt.u[3] = d;                     \
      W[kss] = tt.v;                                                          \
    }                                                                         \
    {                                                                         \
      u32 a = pk1[4 * kss], b = pk1[4 * kss + 2];                             \
      u32 c = pk1[4 * kss + 1], d = pk1[4 * kss + 3];                         \
      pswap(a, b);                                                            \
      pswap(c, d);                                                            \
      union { u32 u[4]; bf16x8 v; } tt;                                       \
      tt.u[0] = a; tt.u[1] = c; tt.u[2] = b; tt.u[3] = d;                     \
      W[2 + kss] = tt.v;                                                      \
    }                                                                         \
  }

#define ATTN_BODY(CB, PF)                                                       \
  {                                                                             \
    if (PF) {                                                                   \
      gload16(pKn, &Ks[(CB) ^ 1][wid * 16][0]);                                 \
      gload16(pKn + 8 * HD, &Ks[(CB) ^ 1][wid * 16 + 8][0]);                    \
      gload16(pVn, &Vs[(CB) ^ 1][wid * 16][0]);                                 \
      gload16(pVn + 8 * SEQ, &Vs[(CB) ^ 1][wid * 16 + 8][0]);                   \
      pKn += 64 * HD;                                                           \
      pVn += 64;                                                                \
    }                                                                           \
    f32x16 sA0, sA1, sB0, sB1;                                                  \
    __builtin_amdgcn_s_setprio(1);                                              \
    {                                                                           \
      bf16x8 ka0 = *(const bf16x8*)(KsB + (CB) * 8192 + roff[0]);               \
      bf16x8 ka1 = *(const bf16x8*)(KsB + (CB) * 8192 + roff[1]);               \
      sA0 = __builtin_amdgcn_mfma_f32_32x32x16_bf16(ka0, qfA[0], zv, 0, 0, 0);  \
      sA1 = __builtin_amdgcn_mfma_f32_32x32x16_bf16(ka1, qfA[0], zv, 0, 0, 0);  \
      sB0 = __builtin_amdgcn_mfma_f32_32x32x16_bf16(ka0, qfB[0], zv, 0, 0, 0);  \
      sB1 = __builtin_amdgcn_mfma_f32_32x32x16_bf16(ka1, qfB[0], zv, 0, 0, 0);  \
    }                                                                           \
    _Pragma("unroll")                                                           \
    for (int ks = 1; ks < 4; ++ks) {                                            \
      bf16x8 ka0 = *(const bf16x8*)(KsB + (CB) * 8192 + roff[ks * 2]);          \
      bf16x8 ka1 = *(const bf16x8*)(KsB + (CB) * 8192 + roff[ks * 2 + 1]);      \
      sA0 = __builtin_amdgcn_mfma_f32_32x32x16_bf16(ka0, qfA[ks], sA0, 0, 0, 0);\
      sA1 = __builtin_amdgcn_mfma_f32_32x32x16_bf16(ka1, qfA[ks], sA1, 0, 0, 0);\
      sB0 = __builtin_amdgcn_mfma_f32_32x32x16_bf16(ka0, qfB[ks], sB0, 0, 0, 0);\
      sB1 = __builtin_amdgcn_mfma_f32_32x32x16_bf16(ka1, qfB[ks], sB1, 0, 0, 0);\
    }                                                                           \
    __builtin_amdgcn_s_setprio(0);                                              \
    _Pragma("unroll")                                                           \
    for (int j = 0; j < 16; ++j) sA0[j] = fexp2(sA0[j]);                        \
    _Pragma("unroll")                                                           \
    for (int j = 0; j < 16; ++j) sA1[j] = fexp2(sA1[j]);                        \
    _Pragma("unroll")                                                           \
    for (int j = 0; j < 16; ++j) sB0[j] = fexp2(sB0[j]);                        \
    _Pragma("unroll")                                                           \
    for (int j = 0; j < 16; ++j) sB1[j] = fexp2(sB1[j]);                        \
    lsumA += vsum16(sA0) + vsum16(sA1);                                         \
    lsumB += vsum16(sB0) + vsum16(sB1);                                         \
    u32 pkA0[8], pkA1[8], pkB0[8], pkB1[8];                                     \
    _Pragma("unroll")                                                           \
    for (int i2 = 0; i2 < 8; ++i2) {                                            \
      pkA0[i2] = cvtpk(sA0[2 * i2], sA0[2 * i2 + 1]);                           \
      pkA1[i2] = cvtpk(sA1[2 * i2], sA1[2 * i2 + 1]);                           \
      pkB0[i2] = cvtpk(sB0[2 * i2], sB0[2 * i2 + 1]);                           \
      pkB1[i2] = cvtpk(sB1[2 * i2], sB1[2 * i2 + 1]);                           \
    }                                                                           \
    bf16x8 WA[4], WB[4];                                                        \
    PACK_W(WA, pkA0, pkA1)                                                      \
    PACK_W(WB, pkB0, pkB1)                                                      \
    __builtin_amdgcn_s_setprio(1);                                              \
    _Pragma("unroll")                                                           \
    for (int ks = 0; ks < 4; ++ks) {                                            \
      bf16x8 va0 = *(const bf16x8*)(VsB + (CB) * 8192 + roff[ks * 2]);          \
      bf16x8 va1 = *(const bf16x8*)(VsB + (CB) * 8192 + roff[ks * 2 + 1]);      \
      oA0 = __builtin_amdgcn_mfma_f32_32x32x16_bf16(va0, WA[ks], oA0, 0, 0, 0); \
      oA1 = __builtin_amdgcn_mfma_f32_32x32x16_bf16(va1, WA[ks], oA1, 0, 0, 0); \
      oB0 = __builtin_amdgcn_mfma_f32_32x32x16_bf16(va0, WB[ks], oB0, 0, 0, 0); \
      oB1 = __builtin_amdgcn_mfma_f32_32x32x16_bf16(va1, WB[ks], oB1, 0, 0, 0); \
    }                                                                           \
    __builtin_amdgcn_s_setprio(0);                                              \
    __syncthreads();                                                            \
  }

  for (int t = 0; t < NT; t += 2) {
    ATTN_BODY(0, true);
    ATTN_BODY(1, (t + 2 < NT));
  }
#undef ATTN_BODY
#undef PACK_W

  // epilogue: one cross-half reduce per q-block, then normalized partial o
  lsumA += __shfl_xor(lsumA, 32);
  lsumB += __shfl_xor(lsumB, 32);
  float invA = 1.f / lsumA;
  float invB = 1.f / lsumB;
  size_t ridxA = (size_t)(kv * 16 + h) * 4096 + qbase + q5;
  size_t ridxB = ridxA + 32;
  u16* cpA = po + ridxA * 64;
  u16* cpB = po + ridxB * 64;
#pragma unroll
  for (int rg = 0; rg < 4; ++rg) {
    ushort4 pa, pb;
    pa.x = f2bf(oA0[rg * 4 + 0] * invA); pa.y = f2bf(oA0[rg * 4 + 1] * invA);
    pa.z = f2bf(oA0[rg * 4 + 2] * invA); pa.w = f2bf(oA0[rg * 4 + 3] * invA);
    pb.x = f2bf(oA1[rg * 4 + 0] * invA); pb.y = f2bf(oA1[rg * 4 + 1] * invA);
    pb.z = f2bf(oA1[rg * 4 + 2] * invA); pb.w = f2bf(oA1[rg * 4 + 3] * invA);
    *(ushort4*)(cpA + rg * 8 + 4 * hi) = pa;
    *(ushort4*)(cpA + 32 + rg * 8 + 4 * hi) = pb;
    pa.x = f2bf(oB0[rg * 4 + 0] * invB); pa.y = f2bf(oB0[rg * 4 + 1] * invB);
    pa.z = f2bf(oB0[rg * 4 + 2] * invB); pa.w = f2bf(oB0[rg * 4 + 3] * invB);
    pb.x = f2bf(oB1[rg * 4 + 0] * invB); pb.y = f2bf(oB1[rg * 4 + 1] * invB);
    pb.z = f2bf(oB1[rg * 4 + 2] * invB); pb.w = f2bf(oB1[rg * 4 + 3] * invB);
    *(ushort4*)(cpB + rg * 8 + 4 * hi) = pa;
    *(ushort4*)(cpB + 32 + rg * 8 + 4 * hi) = pb;
  }
  if (hi == 0) {
    pl[ridxA] = lsumA;
    pl[ridxB] = lsumB;
  }
}

// ---------------- combine two KV-half partials -> ctx ----------------
__global__ __launch_bounds__(256) void combine(
    const u16* __restrict__ po, const float* __restrict__ pl,
    u16* __restrict__ cx) {
  const int tid = threadIdx.x;
  const int R = blockIdx.x * 64 + (tid >> 2);   // row = h*4096 + q
  const int h = R >> 12, q = R & 4095;
  const int dbase = (tid & 3) * 16;
  const int idx0 = R;
  const int idx1 = R + 16 * 4096;
  float l0 = pl[idx0], l1 = pl[idx1];
  float inv = 1.f / (l0 + l1);
  float a0 = l0 * inv, a1 = l1 * inv;
  const u16* p0 = po + (size_t)idx0 * 64 + dbase;
  const u16* p1 = po + (size_t)idx1 * 64 + dbase;
  u16* cp = cx + (size_t)q * DIM + h * 64 + dbase;
#pragma unroll
  for (int v = 0; v < 2; ++v) {
    bf16x8 x0 = *(const bf16x8*)(p0 + v * 8);
    bf16x8 x1 = *(const bf16x8*)(p1 + v * 8);
    union { u16 u[8]; bf16x8 v8; } r;
#pragma unroll
    for (int j = 0; j < 8; ++j)
      r.u[j] = f2bf(a0 * bf2f((u16)x0[j]) + a1 * bf2f((u16)x1[j]));
    *(bf16x8*)(cp + v * 8) = r.v8;
  }
}

extern "C" void kernel_launch(void* const* d_in, const int* in_sizes, int n_in,
                              void* d_out, int out_size, void* d_ws, size_t ws_size,
                              hipStream_t stream) {
  const float* query = (const float*)d_in[0];
  const float* key_  = (const float*)d_in[1];
  const float* value = (const float*)d_in[2];
  const float* Wq = (const float*)d_in[3]; const float* bq = (const float*)d_in[4];
  const float* Wk = (const float*)d_in[5]; const float* bk = (const float*)d_in[6];
  const float* Wv = (const float*)d_in[7]; const float* bv = (const float*)d_in[8];
  const float* Wo = (const float*)d_in[9]; const float* bo = (const float*)d_in[10];

  char* ws = (char*)d_ws;
  const size_t MB = 1024 * 1024;
  u16* qx = (u16*)(ws);            // 8MB  (dead after gemm_proj)
  u16* kx = (u16*)(ws + 8 * MB);   // 8MB  (dead after gemm_proj)
  u16* vx = (u16*)(ws + 16 * MB);  // 8MB  (dead after gemm_proj)
  u16* wq = (u16*)(ws + 24 * MB);  // 2MB
  u16* wk = (u16*)(ws + 26 * MB);
  u16* wv = (u16*)(ws + 28 * MB);
  u16* wo = (u16*)(ws + 30 * MB);  // live until gemm_out
  u16* Qb = (u16*)(ws + 32 * MB);  // 8MB  (h, s, d)  pre-scaled by 0.125*log2(e)
  u16* Kb = (u16*)(ws + 40 * MB);  // 8MB  (h, l, d)
  u16* Vt = (u16*)(ws + 48 * MB);  // 8MB  (h, d, l)
  u16* cx = (u16*)(ws + 56 * MB);  // 8MB  ctx bf16 (s, DIM)
  u16* po = (u16*)(ws);            // 16MB partial o [kv][h][q][64] (overlaps qx/kx)
  float* pl = (float*)(ws + 16 * MB);  // 512KB [kv][h][q]

  cvt_all<<<dim3(16384), 256, 0, stream>>>(query, key_, value, Wq, Wk, Wv, Wo,
                                           qx, kx, vx, wq, wk, wv, wo);

  gemm_proj<<<dim3(256, 3), 256, 0, stream>>>(qx, kx, vx, wq, wk, wv,
                                              bq, bk, bv, Qb, Kb, Vt);

  attn32<<<dim3(512), 256, 0, stream>>>(Qb, Kb, Vt, po, pl);

  combine<<<dim3(1024), 256, 0, stream>>>(po, pl, cx);

  gemm_out<<<dim3(64, 8), 256, 0, stream>>>(cx, wo, bo, (float*)d_out);
}